// Round 16
// baseline (2932.771 us; speedup 1.0000x reference)
//
#include <hip/hip_runtime.h>
#include <hip/hip_bf16.h>
#include <math.h>

#define Bk 8
#define Nk 10000
#define Hk 64
#define Lk 4
#define Rk 3
#define Ek 200000
#define FPk 2048

#define CNTB ((Rk*Ek + 255)/256)   /* 2344 count/fill blocks */
#define INITB 2048
#define AGGB  30000                /* 4 bpair-major ranges x 7500 */
#define NTILE ((Nk + 127)/128)     /* 79 proj tiles */
#define PROJB (NTILE*8)            /* 632 proj blocks */

typedef unsigned short u16;
typedef unsigned int   u32;
typedef _Float16 f16;
typedef __attribute__((ext_vector_type(2))) _Float16 f16x2;
typedef __attribute__((ext_vector_type(8))) _Float16 f16x8;
typedef __attribute__((ext_vector_type(4))) float f32x4;

__device__ __forceinline__ f16x2 as_h2(u32 u){
    union{u32 i; f16x2 h;} v; v.i = u; return v.h;
}
__device__ __forceinline__ u32 as_u32(f16x2 h){
    union{u32 i; f16x2 h;} v; v.h = h; return v.i;
}
__device__ __forceinline__ u16 f2h_bits(float f){
    union{f16 h; u16 u;} v; v.h = (f16)f; return v.u;
}

// ---------------------------------------------------------------------------
// Weight prep (fp16, MFMA B layout) + deg + layer-counter zeroing.
// Grid covers 65536 threads (wt), which also covers deg (30000) and cnt (16).
// ---------------------------------------------------------------------------
__global__ void k_wprep(const float* __restrict__ Wself, const float* __restrict__ Wrel,
                        u16* __restrict__ wt, int* __restrict__ deg, int* __restrict__ cnt){
    int idx = blockIdx.x*256 + threadIdx.x;
    if(idx < Rk*Nk) deg[idx] = 0;
    if(idx < 16) cnt[idx] = 0;
    if(idx >= Lk*4*2*4*64*8) return;
    int j    = idx & 7;
    int lane = (idx >> 3) & 63;
    int jt   = (idx >> 9) & 3;
    int kc   = (idx >> 11) & 1;
    int mt   = (idx >> 12) & 3;
    int l    = idx >> 14;
    int k    = kc*32 + (lane >> 4)*8 + j;
    int col  = jt*16 + (lane & 15);
    float w = (mt == 0) ? Wself[(l*64 + k)*64 + col]
                        : Wrel[((l*3 + (mt-1))*64 + k)*64 + col];
    wt[idx] = f2h_bits(w);
}

// ---------------------------------------------------------------------------
// Fused: deg count (blocks < CNTB) + FiLM stage 1 (512 blocks after)
// ---------------------------------------------------------------------------
__global__ void k_count_film1(const int* __restrict__ edge_index, int* __restrict__ deg,
                              const float* __restrict__ fp, const float* __restrict__ W1,
                              const float* __restrict__ b1, float* __restrict__ hid){
    __shared__ float red[256];
    if(blockIdx.x < CNTB){
        int idx = blockIdx.x*256 + threadIdx.x;
        if(idx >= Rk*Ek) return;
        int r = idx / Ek, e = idx % Ek;
        int dst = edge_index[r*2*Ek + Ek + e];
        atomicAdd(&deg[r*Nk + dst], 1);
    }else{
        int bb = blockIdx.x - CNTB;            // 0..511
        int b = bb >> 6, h = bb & 63;
        const float* fpb = fp + b*FPk;
        float acc = 0.f;
        for(int k = threadIdx.x; k < FPk; k += 256)
            acc += fpb[k] * W1[k*64 + h];
        red[threadIdx.x] = acc;
        __syncthreads();
        for(int s = 128; s >= 1; s >>= 1){
            if(threadIdx.x < s) red[threadIdx.x] += red[threadIdx.x + s];
            __syncthreads();
        }
        if(threadIdx.x == 0) hid[b*64 + h] = fmaxf(red[0] + b1[h], 0.f);
    }
}

// ---------------------------------------------------------------------------
// Fused: CSR scan (blocks 0..2, 1024 thr) + FiLM stage 2 (blocks 3..10)
// ---------------------------------------------------------------------------
__global__ void k_scan_film2(const int* __restrict__ deg, int* __restrict__ offs,
                             int* __restrict__ cursor,
                             const float* __restrict__ hid, const float* __restrict__ W2,
                             const float* __restrict__ b2,
                             float* __restrict__ g1p, float* __restrict__ beta){
    __shared__ int s[1024];
    if(blockIdx.x < 3){
        int r = blockIdx.x;
        int t = threadIdx.x;
        int base_i = t*10;
        int local[10];
        int sum = 0;
        if(base_i < Nk){
            #pragma unroll
            for(int k = 0; k < 10; ++k){ local[k] = deg[r*Nk + base_i + k]; sum += local[k]; }
        }
        s[t] = sum;
        __syncthreads();
        for(int d = 1; d < 1024; d <<= 1){
            int v = (t >= d) ? s[t-d] : 0;
            __syncthreads();
            s[t] += v;
            __syncthreads();
        }
        if(base_i < Nk){
            int excl = s[t] - sum;
            #pragma unroll
            for(int k = 0; k < 10; ++k){
                offs[r*(Nk+1) + base_i + k] = excl;
                cursor[r*Nk + base_i + k]   = excl;
                excl += local[k];
            }
        }
        if(t == 1023) offs[r*(Nk+1) + Nk] = s[1023];
    }else{
        int b = blockIdx.x - 3;                // 0..7
        int j = threadIdx.x;
        if(j < 128){
            float acc = b2[j];
            for(int k = 0; k < 64; ++k)
                acc += hid[b*64 + k] * W2[k*128 + j];
            if(j < 64) g1p[b*64 + j] = 1.f + tanhf(acc);
            else       beta[b*64 + j - 64] = acc;
        }
    }
}

// ---------------------------------------------------------------------------
// Fused: CSR fill (blocks < CNTB) + x0 init (INITB blocks after)
// ---------------------------------------------------------------------------
__global__ void k_fill_init(const int* __restrict__ edge_index, const float* __restrict__ edge_weight,
                            int* __restrict__ cursor, int2* __restrict__ epack,
                            const float* __restrict__ ctl, const float* __restrict__ dt,
                            const int* __restrict__ cell_idx,
                            const float* __restrict__ W_se, const float* __restrict__ b_se,
                            const float* __restrict__ cell_emb,
                            const float* __restrict__ g1p, const float* __restrict__ beta,
                            u16* __restrict__ xh){
    if(blockIdx.x < CNTB){
        int idx = blockIdx.x*256 + threadIdx.x;
        if(idx >= Rk*Ek) return;
        int r = idx / Ek, e = idx % Ek;
        int src = edge_index[r*2*Ek + e];
        int dst = edge_index[r*2*Ek + Ek + e];
        int pos = atomicAdd(&cursor[r*Nk + dst], 1);
        f16 h = (f16)edge_weight[r*Ek + e];
        epack[(size_t)r*Ek + pos] = make_int2(src << 7, (int)as_u32((f16x2){h, h}));
    }else{
        const size_t total = (size_t)Bk*Nk*64;
        size_t start = (size_t)(blockIdx.x - CNTB)*256 + threadIdx.x;
        for(size_t i = start; i < total; i += (size_t)INITB*256){
            int h = (int)(i & 63);
            size_t bn = i >> 6;
            int b = (int)(bn / Nk);
            float w = W_se[h], bs = b_se[h];
            float v = fmaxf(ctl[bn]*w + bs, 0.f) + fmaxf(dt[bn]*w + bs, 0.f)
                    + cell_emb[cell_idx[b]*64 + h];
            xh[i] = f2h_bits(v * g1p[b*64 + h] + beta[b*64 + h]);
        }
    }
}

// ---------------------------------------------------------------------------
// FUSED per-layer kernel: agg blocks (bpair-major) + proj blocks overlapped
// via per-bpair release/acquire counters. aggh/xh stores are nontemporal
// (L2-bypass -> L3 coherence point) so cross-XCD reads are never stale.
// Deadlock-free: PROJB(632) spinners < resident capacity -> agg always runs.
// ---------------------------------------------------------------------------
__global__ __launch_bounds__(256) void k_layer(u16* __restrict__ xh,
        u16* __restrict__ aggh, int* __restrict__ cnt,
        const int* __restrict__ offs, const int2* __restrict__ epack,
        const u16* __restrict__ wt,
        const float* __restrict__ ln_g, const float* __restrict__ ln_b, int l,
        int last, const float* __restrict__ W_out, const float* __restrict__ b_out,
        float* __restrict__ out){
    __shared__ int2 stash[4][64];

    if(blockIdx.x < AGGB){
        // ---------------- agg producer (R11/R15-proven inner loop) ----------------
        int bpair = blockIdx.x / 7500;             // bpair-major: bpair 0 retires first
        int grp   = blockIdx.x % 7500;
        int wq    = threadIdx.x >> 6;
        int wid   = grp*4 + wq;                    // 0..29999 = (r,dst)
        int lane  = threadIdx.x & 63;
        int fg    = lane & 31;
        int bl    = lane >> 5;
        int b     = bpair*2 + bl;
        int r = wid / Nk, dst = wid % Nk;
        int o0 = offs[r*(Nk+1) + dst], o1 = offs[r*(Nk+1) + dst + 1];
        const int2* ep = epack + (size_t)r*Ek;
        const char* xb = (const char*)xh + (size_t)b*Nk*128 + fg*4;

        f16x2 A = (f16x2){0,0}, C = (f16x2){0,0};
        int2* st = stash[wq];
        for(int base = o0; base < o1; base += 64){
            int j = base + lane;
            if(j < o1) st[lane] = ep[j];
            int cnt2 = min(o1 - base, 64);
            int t = 0;
            for(; t + 8 <= cnt2; t += 8){
                int4 q01 = *(const int4*)&st[t];
                int4 q23 = *(const int4*)&st[t+2];
                int4 q45 = *(const int4*)&st[t+4];
                int4 q67 = *(const int4*)&st[t+6];
                u32 u0 = *(const u32*)(xb + q01.x);
                u32 u1 = *(const u32*)(xb + q01.z);
                u32 u2 = *(const u32*)(xb + q23.x);
                u32 u3 = *(const u32*)(xb + q23.z);
                u32 u4 = *(const u32*)(xb + q45.x);
                u32 u5 = *(const u32*)(xb + q45.z);
                u32 u6 = *(const u32*)(xb + q67.x);
                u32 u7 = *(const u32*)(xb + q67.z);
                A += as_h2(u0)*as_h2(q01.y); C += as_h2(u1)*as_h2(q01.w);
                A += as_h2(u2)*as_h2(q23.y); C += as_h2(u3)*as_h2(q23.w);
                A += as_h2(u4)*as_h2(q45.y); C += as_h2(u5)*as_h2(q45.w);
                A += as_h2(u6)*as_h2(q67.y); C += as_h2(u7)*as_h2(q67.w);
            }
            for(; t + 2 <= cnt2; t += 2){
                int4 q01 = *(const int4*)&st[t];
                u32 u0 = *(const u32*)(xb + q01.x);
                u32 u1 = *(const u32*)(xb + q01.z);
                A += as_h2(u0)*as_h2(q01.y); C += as_h2(u1)*as_h2(q01.w);
            }
            if(t < cnt2){
                int2 p = st[t];
                u32 u = *(const u32*)(xb + p.x);
                A += as_h2(u)*as_h2(p.y);
            }
        }
        float a0 = (float)A.x + (float)C.x;
        float a1 = (float)A.y + (float)C.y;
        u32 packed = (u32)f2h_bits(a0) | ((u32)f2h_bits(a1) << 16);
        __builtin_nontemporal_store(packed,
            &((u32*)aggh)[(((size_t)r*Bk + b)*Nk + dst)*32 + fg]);

        __syncthreads();   // drains all waves' stores (compiler emits vmcnt(0) before barrier)
        if(threadIdx.x == 0)
            __hip_atomic_fetch_add(&cnt[bpair], 1, __ATOMIC_RELEASE, __HIP_MEMORY_SCOPE_AGENT);
    }else{
        // ---------------- proj consumer (2-tile MFMA + LN + readout) ----------------
        int pb   = blockIdx.x - AGGB;
        int b    = pb & 7;
        int bpair = b >> 1;
        int tile = pb >> 3;

        if(threadIdx.x == 0){
            while(__hip_atomic_load(&cnt[bpair], __ATOMIC_ACQUIRE, __HIP_MEMORY_SCOPE_AGENT) < 7500)
                __builtin_amdgcn_s_sleep(32);
        }
        __syncthreads();

        int lane = threadIdx.x & 63;
        int wq   = threadIdx.x >> 6;
        int n0   = tile*128 + wq*32;
        int mrow = lane & 15;
        int kq   = lane >> 4;
        int nA = n0 + mrow;       if(nA >= Nk) nA = Nk - 1;
        int nB = n0 + 16 + mrow;  if(nB >= Nk) nB = Nk - 1;

        f32x4 accA[4], accB[4];
        #pragma unroll
        for(int jt = 0; jt < 4; ++jt){
            accA[jt] = (f32x4){0.f,0.f,0.f,0.f};
            accB[jt] = (f32x4){0.f,0.f,0.f,0.f};
        }

        const u16* wl = wt + (size_t)l*16384;

        #pragma unroll
        for(int mt = 0; mt < 4; ++mt){
            const u16* basep = (mt == 0)
                ? xh   + (size_t)b*Nk*64
                : aggh + (((size_t)(mt-1)*Bk + b)*Nk)*64;
            const u16* arowA = basep + (size_t)nA*64;
            const u16* arowB = basep + (size_t)nB*64;
            #pragma unroll
            for(int kc = 0; kc < 2; ++kc){
                f16x8 aA = *(const f16x8*)(arowA + kc*32 + kq*8);
                f16x8 aB = *(const f16x8*)(arowB + kc*32 + kq*8);
                #pragma unroll
                for(int jt = 0; jt < 4; ++jt){
                    size_t wi = ((size_t)((mt*2 + kc)*4 + jt)*64 + lane)*8;
                    f16x8 bfrag = *(const f16x8*)(wl + wi);
                    accA[jt] = __builtin_amdgcn_mfma_f32_16x16x32_f16(aA, bfrag, accA[jt], 0, 0, 0);
                    accB[jt] = __builtin_amdgcn_mfma_f32_16x16x32_f16(aB, bfrag, accB[jt], 0, 0, 0);
                }
            }
        }

        float gv[4], bv[4], wo[4];
        #pragma unroll
        for(int jt = 0; jt < 4; ++jt){
            int f = jt*16 + mrow;
            gv[jt] = ln_g[l*64 + f];
            bv[jt] = ln_b[l*64 + f];
            wo[jt] = W_out[f];
        }
        float bo = b_out[0];
        u16* xdst = xh + (size_t)b*Nk*64;

        #pragma unroll
        for(int half = 0; half < 2; ++half){
            f32x4* acc = half ? accB : accA;
            int nbase = n0 + half*16;
            #pragma unroll
            for(int v = 0; v < 4; ++v){
                float s1 = acc[0][v] + acc[1][v] + acc[2][v] + acc[3][v];
                float s2 = acc[0][v]*acc[0][v] + acc[1][v]*acc[1][v]
                         + acc[2][v]*acc[2][v] + acc[3][v]*acc[3][v];
                #pragma unroll
                for(int off = 1; off <= 8; off <<= 1){
                    s1 += __shfl_xor(s1, off);
                    s2 += __shfl_xor(s2, off);
                }
                float mu  = s1 * 0.015625f;
                float var = s2 * 0.015625f - mu*mu;
                float rstd = rsqrtf(var + 1e-3f);
                int node = nbase + kq*4 + v;
                if(!last){
                    if(node < Nk){
                        #pragma unroll
                        for(int jt = 0; jt < 4; ++jt){
                            float o = (acc[jt][v] - mu) * rstd * gv[jt] + bv[jt];
                            __builtin_nontemporal_store(f2h_bits(fmaxf(o, 0.f)),
                                &xdst[(size_t)node*64 + jt*16 + mrow]);
                        }
                    }
                }else{
                    float s3 = 0.f;
                    #pragma unroll
                    for(int jt = 0; jt < 4; ++jt){
                        float o = (acc[jt][v] - mu) * rstd * gv[jt] + bv[jt];
                        s3 += fmaxf(o, 0.f) * wo[jt];
                    }
                    #pragma unroll
                    for(int off = 1; off <= 8; off <<= 1)
                        s3 += __shfl_xor(s3, off);
                    if(mrow == 0 && node < Nk)
                        out[(size_t)b*Nk + node] = s3 + bo;
                }
            }
        }
    }
}

// ---------------------------------------------------------------------------
extern "C" void kernel_launch(void* const* d_in, const int* in_sizes, int n_in,
                              void* d_out, int out_size, void* d_ws, size_t ws_size,
                              hipStream_t stream){
    const float* ctl        = (const float*)d_in[0];
    const float* dt         = (const float*)d_in[1];
    const float* drug_fp    = (const float*)d_in[2];
    const float* edge_w     = (const float*)d_in[3];
    const int*   cell_idx   = (const int*)  d_in[4];
    const int*   edge_index = (const int*)  d_in[5];
    const float* W_se       = (const float*)d_in[6];
    const float* b_se       = (const float*)d_in[7];
    const float* cell_emb   = (const float*)d_in[8];
    const float* W_f1       = (const float*)d_in[9];
    const float* b_f1       = (const float*)d_in[10];
    const float* W_f2       = (const float*)d_in[11];
    const float* b_f2       = (const float*)d_in[12];
    const float* Wself      = (const float*)d_in[13];
    const float* Wrel       = (const float*)d_in[14];
    const float* ln_g       = (const float*)d_in[15];
    const float* ln_b       = (const float*)d_in[16];
    const float* W_out      = (const float*)d_in[17];
    const float* b_out      = (const float*)d_in[18];
    float* out = (float*)d_out;

    char* p = (char*)d_ws;
    auto alloc = [&](size_t bytes)->char*{
        char* r = p; p += (bytes + 255) & ~(size_t)255; return r;
    };
    int*   deg    = (int*)  alloc((size_t)Rk*Nk*4);
    int*   cursor = (int*)  alloc((size_t)Rk*Nk*4);
    int*   offs   = (int*)  alloc((size_t)Rk*(Nk+1)*4);
    int2*  epack  = (int2*) alloc((size_t)Rk*Ek*8);
    float* hid    = (float*)alloc((size_t)Bk*64*4);
    float* g1p    = (float*)alloc((size_t)Bk*64*4);
    float* beta   = (float*)alloc((size_t)Bk*64*4);
    u16*   xh     = (u16*)  alloc((size_t)Bk*Nk*64*2);
    u16*   aggh   = (u16*)  alloc((size_t)3*Bk*Nk*64*2);
    u16*   wt     = (u16*)  alloc((size_t)Lk*16384*2);
    int*   cnt    = (int*)  alloc(16*4);

    // weight prep + deg/counter zeroing (65536 threads covers wt, deg, cnt)
    k_wprep<<<(Lk*4*2*4*64*8 + 255)/256, 256, 0, stream>>>(Wself, Wrel, wt, deg, cnt);

    // fused prep pipeline
    k_count_film1<<<CNTB + Bk*64, 256, 0, stream>>>(edge_index, deg, drug_fp, W_f1, b_f1, hid);
    k_scan_film2<<<3 + Bk, 1024, 0, stream>>>(deg, offs, cursor, hid, W_f2, b_f2, g1p, beta);
    k_fill_init<<<CNTB + INITB, 256, 0, stream>>>(edge_index, edge_w, cursor, epack,
                                                  ctl, dt, cell_idx, W_se, b_se, cell_emb,
                                                  g1p, beta, xh);

    // fused overlapped layers (agg producers + proj consumers in one dispatch)
    for(int l = 0; l < Lk; ++l){
        k_layer<<<AGGB + PROJB, 256, 0, stream>>>(
            xh, aggh, cnt + l*4, offs, epack, wt, ln_g, ln_b, l,
            (l == Lk-1) ? 1 : 0, W_out, b_out, out);
    }
}

// Round 17
// 410.071 us; speedup vs baseline: 7.1519x; 7.1519x over previous
//
#include <hip/hip_runtime.h>
#include <hip/hip_bf16.h>
#include <math.h>

#define Bk 8
#define Nk 10000
#define Hk 64
#define Lk 4
#define Rk 3
#define Ek 200000
#define FPk 2048

#define CNTB ((Rk*Ek + 255)/256)   /* 2344 count/fill blocks */
#define INITB 2048

typedef unsigned short u16;
typedef unsigned int   u32;
typedef _Float16 f16;
typedef __attribute__((ext_vector_type(2))) _Float16 f16x2;
typedef __attribute__((ext_vector_type(8))) _Float16 f16x8;
typedef __attribute__((ext_vector_type(4))) float f32x4;

__device__ __forceinline__ f16x2 as_h2(u32 u){
    union{u32 i; f16x2 h;} v; v.i = u; return v.h;
}
__device__ __forceinline__ u32 as_u32(f16x2 h){
    union{u32 i; f16x2 h;} v; v.h = h; return v.i;
}
__device__ __forceinline__ u16 f2h_bits(float f){
    union{f16 h; u16 u;} v; v.h = (f16)f; return v.u;
}

// ---------------------------------------------------------------------------
// Weight prep (fp16, MFMA B layout) + deg zeroing. Grid covers 65536 threads.
// ---------------------------------------------------------------------------
__global__ void k_wprep(const float* __restrict__ Wself, const float* __restrict__ Wrel,
                        u16* __restrict__ wt, int* __restrict__ deg){
    int idx = blockIdx.x*256 + threadIdx.x;
    if(idx < Rk*Nk) deg[idx] = 0;
    if(idx >= Lk*4*2*4*64*8) return;
    int j    = idx & 7;
    int lane = (idx >> 3) & 63;
    int jt   = (idx >> 9) & 3;
    int kc   = (idx >> 11) & 1;
    int mt   = (idx >> 12) & 3;
    int l    = idx >> 14;
    int k    = kc*32 + (lane >> 4)*8 + j;
    int col  = jt*16 + (lane & 15);
    float w = (mt == 0) ? Wself[(l*64 + k)*64 + col]
                        : Wrel[((l*3 + (mt-1))*64 + k)*64 + col];
    wt[idx] = f2h_bits(w);
}

// ---------------------------------------------------------------------------
// Fused: deg count (blocks < CNTB) + FiLM stage 1 (512 blocks after)
// ---------------------------------------------------------------------------
__global__ void k_count_film1(const int* __restrict__ edge_index, int* __restrict__ deg,
                              const float* __restrict__ fp, const float* __restrict__ W1,
                              const float* __restrict__ b1, float* __restrict__ hid){
    __shared__ float red[256];
    if(blockIdx.x < CNTB){
        int idx = blockIdx.x*256 + threadIdx.x;
        if(idx >= Rk*Ek) return;
        int r = idx / Ek, e = idx % Ek;
        int dst = edge_index[r*2*Ek + Ek + e];
        atomicAdd(&deg[r*Nk + dst], 1);
    }else{
        int bb = blockIdx.x - CNTB;            // 0..511
        int b = bb >> 6, h = bb & 63;
        const float* fpb = fp + b*FPk;
        float acc = 0.f;
        for(int k = threadIdx.x; k < FPk; k += 256)
            acc += fpb[k] * W1[k*64 + h];
        red[threadIdx.x] = acc;
        __syncthreads();
        for(int s = 128; s >= 1; s >>= 1){
            if(threadIdx.x < s) red[threadIdx.x] += red[threadIdx.x + s];
            __syncthreads();
        }
        if(threadIdx.x == 0) hid[b*64 + h] = fmaxf(red[0] + b1[h], 0.f);
    }
}

// ---------------------------------------------------------------------------
// Fused: CSR scan (blocks 0..2, 1024 thr) + FiLM stage 2 (blocks 3..10)
// ---------------------------------------------------------------------------
__global__ void k_scan_film2(const int* __restrict__ deg, int* __restrict__ offs,
                             int* __restrict__ cursor,
                             const float* __restrict__ hid, const float* __restrict__ W2,
                             const float* __restrict__ b2,
                             float* __restrict__ g1p, float* __restrict__ beta){
    __shared__ int s[1024];
    if(blockIdx.x < 3){
        int r = blockIdx.x;
        int t = threadIdx.x;
        int base_i = t*10;
        int local[10];
        int sum = 0;
        if(base_i < Nk){
            #pragma unroll
            for(int k = 0; k < 10; ++k){ local[k] = deg[r*Nk + base_i + k]; sum += local[k]; }
        }
        s[t] = sum;
        __syncthreads();
        for(int d = 1; d < 1024; d <<= 1){
            int v = (t >= d) ? s[t-d] : 0;
            __syncthreads();
            s[t] += v;
            __syncthreads();
        }
        if(base_i < Nk){
            int excl = s[t] - sum;
            #pragma unroll
            for(int k = 0; k < 10; ++k){
                offs[r*(Nk+1) + base_i + k] = excl;
                cursor[r*Nk + base_i + k]   = excl;
                excl += local[k];
            }
        }
        if(t == 1023) offs[r*(Nk+1) + Nk] = s[1023];
    }else{
        int b = blockIdx.x - 3;                // 0..7
        int j = threadIdx.x;
        if(j < 128){
            float acc = b2[j];
            for(int k = 0; k < 64; ++k)
                acc += hid[b*64 + k] * W2[k*128 + j];
            if(j < 64) g1p[b*64 + j] = 1.f + tanhf(acc);
            else       beta[b*64 + j - 64] = acc;
        }
    }
}

// ---------------------------------------------------------------------------
// Fused: CSR fill (blocks < CNTB) + x0 init (INITB blocks after)
// ---------------------------------------------------------------------------
__global__ void k_fill_init(const int* __restrict__ edge_index, const float* __restrict__ edge_weight,
                            int* __restrict__ cursor, int2* __restrict__ epack,
                            const float* __restrict__ ctl, const float* __restrict__ dt,
                            const int* __restrict__ cell_idx,
                            const float* __restrict__ W_se, const float* __restrict__ b_se,
                            const float* __restrict__ cell_emb,
                            const float* __restrict__ g1p, const float* __restrict__ beta,
                            u16* __restrict__ xh){
    if(blockIdx.x < CNTB){
        int idx = blockIdx.x*256 + threadIdx.x;
        if(idx >= Rk*Ek) return;
        int r = idx / Ek, e = idx % Ek;
        int src = edge_index[r*2*Ek + e];
        int dst = edge_index[r*2*Ek + Ek + e];
        int pos = atomicAdd(&cursor[r*Nk + dst], 1);
        f16 h = (f16)edge_weight[r*Ek + e];
        epack[(size_t)r*Ek + pos] = make_int2(src << 7, (int)as_u32((f16x2){h, h}));
    }else{
        const size_t total = (size_t)Bk*Nk*64;
        size_t start = (size_t)(blockIdx.x - CNTB)*256 + threadIdx.x;
        for(size_t i = start; i < total; i += (size_t)INITB*256){
            int h = (int)(i & 63);
            size_t bn = i >> 6;
            int b = (int)(bn / Nk);
            float w = W_se[h], bs = b_se[h];
            float v = fmaxf(ctl[bn]*w + bs, 0.f) + fmaxf(dt[bn]*w + bs, 0.f)
                    + cell_emb[cell_idx[b]*64 + h];
            xh[i] = f2h_bits(v * g1p[b*64 + h] + beta[b*64 + h]);
        }
    }
}

// ---------------------------------------------------------------------------
// agg (fp16): wave = one (r,dst) x 2 batches (lane>>5) x 32 feat-dwords (lane&31).
// R11-proven: 120k waves, LDS stash, 8 gathers in flight, pk_fma.
// bpair=blockIdx&3 -> per-XCD 2.56MB slice (L2-hit). At the measured L2
// random-row throughput floor (~12.7 TB/s, R10/R11/R15 invariance).
// ---------------------------------------------------------------------------
__global__ __launch_bounds__(256) void k_agg(const u16* __restrict__ xh,
                      const int* __restrict__ offs, const int2* __restrict__ epack,
                      u16* __restrict__ aggh){
    __shared__ int2 stash[4][64];
    int bpair = blockIdx.x & 3;
    int grp   = blockIdx.x >> 2;                   // 0..7499
    int wq    = threadIdx.x >> 6;
    int wid   = grp*4 + wq;                        // 0..29999 = (r,dst)
    int lane  = threadIdx.x & 63;
    int fg    = lane & 31;                         // feat dword: feats fg*2, fg*2+1
    int bl    = lane >> 5;                         // local batch 0/1
    int b     = bpair*2 + bl;
    int r = wid / Nk, dst = wid % Nk;
    int o0 = offs[r*(Nk+1) + dst], o1 = offs[r*(Nk+1) + dst + 1];
    const int2* ep = epack + (size_t)r*Ek;
    const char* xb = (const char*)xh + (size_t)b*Nk*128 + fg*4;

    f16x2 A = (f16x2){0,0}, C = (f16x2){0,0};      // 2 accumulation chains
    int2* st = stash[wq];
    for(int base = o0; base < o1; base += 64){
        int j = base + lane;
        if(j < o1) st[lane] = ep[j];
        int cnt = min(o1 - base, 64);
        int t = 0;
        for(; t + 8 <= cnt; t += 8){
            int4 q01 = *(const int4*)&st[t];
            int4 q23 = *(const int4*)&st[t+2];
            int4 q45 = *(const int4*)&st[t+4];
            int4 q67 = *(const int4*)&st[t+6];
            u32 u0 = *(const u32*)(xb + q01.x);
            u32 u1 = *(const u32*)(xb + q01.z);
            u32 u2 = *(const u32*)(xb + q23.x);
            u32 u3 = *(const u32*)(xb + q23.z);
            u32 u4 = *(const u32*)(xb + q45.x);
            u32 u5 = *(const u32*)(xb + q45.z);
            u32 u6 = *(const u32*)(xb + q67.x);
            u32 u7 = *(const u32*)(xb + q67.z);
            A += as_h2(u0)*as_h2(q01.y); C += as_h2(u1)*as_h2(q01.w);
            A += as_h2(u2)*as_h2(q23.y); C += as_h2(u3)*as_h2(q23.w);
            A += as_h2(u4)*as_h2(q45.y); C += as_h2(u5)*as_h2(q45.w);
            A += as_h2(u6)*as_h2(q67.y); C += as_h2(u7)*as_h2(q67.w);
        }
        for(; t + 2 <= cnt; t += 2){
            int4 q01 = *(const int4*)&st[t];
            u32 u0 = *(const u32*)(xb + q01.x);
            u32 u1 = *(const u32*)(xb + q01.z);
            A += as_h2(u0)*as_h2(q01.y); C += as_h2(u1)*as_h2(q01.w);
        }
        if(t < cnt){
            int2 p = st[t];
            u32 u = *(const u32*)(xb + p.x);
            A += as_h2(u)*as_h2(p.y);
        }
    }
    float a0 = (float)A.x + (float)C.x;
    float a1 = (float)A.y + (float)C.y;
    u32 packed = (u32)f2h_bits(a0) | ((u32)f2h_bits(a1) << 16);
    ((u32*)aggh)[(((size_t)r*Bk + b)*Nk + dst)*32 + fg] = packed;
}

// ---------------------------------------------------------------------------
// MFMA projection (fp16) + LN + ReLU (+ fused readout on last layer).
// 2 node-tiles per wave (32 nodes): each B-fragment loaded ONCE, used for 2
// MFMAs -> B traffic and per-output issue halved. XCD-aligned grid.
// ---------------------------------------------------------------------------
__global__ __launch_bounds__(256) void k_proj_mfma(u16* __restrict__ xh,
        const u16* __restrict__ aggh, const u16* __restrict__ wt,
        const float* __restrict__ ln_g, const float* __restrict__ ln_b, int l,
        int last, const float* __restrict__ W_out, const float* __restrict__ b_out,
        float* __restrict__ out){
    int lane = threadIdx.x & 63;
    int wq   = threadIdx.x >> 6;
    int k8   = blockIdx.x & 7;
    int b    = ((k8 & 3) << 1) | (k8 >> 2);   // inverse of xcd(b)=(b>>1)+4*(b&1)
    int tile = blockIdx.x >> 3;
    int n0   = tile*128 + wq*32;              // 32 nodes for this wave
    int mrow = lane & 15;
    int kq   = lane >> 4;
    int nA = n0 + mrow;       if(nA >= Nk) nA = Nk - 1;
    int nB = n0 + 16 + mrow;  if(nB >= Nk) nB = Nk - 1;

    f32x4 accA[4], accB[4];
    #pragma unroll
    for(int jt = 0; jt < 4; ++jt){
        accA[jt] = (f32x4){0.f,0.f,0.f,0.f};
        accB[jt] = (f32x4){0.f,0.f,0.f,0.f};
    }

    const u16* wl = wt + (size_t)l*16384;

    #pragma unroll
    for(int mt = 0; mt < 4; ++mt){
        const u16* basep = (mt == 0)
            ? xh   + (size_t)b*Nk*64
            : aggh + (((size_t)(mt-1)*Bk + b)*Nk)*64;
        const u16* arowA = basep + (size_t)nA*64;
        const u16* arowB = basep + (size_t)nB*64;
        #pragma unroll
        for(int kc = 0; kc < 2; ++kc){
            f16x8 aA = *(const f16x8*)(arowA + kc*32 + kq*8);
            f16x8 aB = *(const f16x8*)(arowB + kc*32 + kq*8);
            #pragma unroll
            for(int jt = 0; jt < 4; ++jt){
                size_t wi = ((size_t)((mt*2 + kc)*4 + jt)*64 + lane)*8;
                f16x8 bfrag = *(const f16x8*)(wl + wi);
                accA[jt] = __builtin_amdgcn_mfma_f32_16x16x32_f16(aA, bfrag, accA[jt], 0, 0, 0);
                accB[jt] = __builtin_amdgcn_mfma_f32_16x16x32_f16(aB, bfrag, accB[jt], 0, 0, 0);
            }
        }
    }

    float gv[4], bv[4], wo[4];
    #pragma unroll
    for(int jt = 0; jt < 4; ++jt){
        int f = jt*16 + mrow;
        gv[jt] = ln_g[l*64 + f];
        bv[jt] = ln_b[l*64 + f];
        wo[jt] = W_out[f];
    }
    float bo = b_out[0];
    u16* xdst = xh + (size_t)b*Nk*64;

    #pragma unroll
    for(int half = 0; half < 2; ++half){
        f32x4* acc = half ? accB : accA;
        int nbase = n0 + half*16;
        #pragma unroll
        for(int v = 0; v < 4; ++v){
            float s1 = acc[0][v] + acc[1][v] + acc[2][v] + acc[3][v];
            float s2 = acc[0][v]*acc[0][v] + acc[1][v]*acc[1][v]
                     + acc[2][v]*acc[2][v] + acc[3][v]*acc[3][v];
            #pragma unroll
            for(int off = 1; off <= 8; off <<= 1){
                s1 += __shfl_xor(s1, off);
                s2 += __shfl_xor(s2, off);
            }
            float mu  = s1 * 0.015625f;
            float var = s2 * 0.015625f - mu*mu;
            float rstd = rsqrtf(var + 1e-3f);
            int node = nbase + kq*4 + v;
            if(!last){
                if(node < Nk){
                    #pragma unroll
                    for(int jt = 0; jt < 4; ++jt){
                        float o = (acc[jt][v] - mu) * rstd * gv[jt] + bv[jt];
                        xdst[(size_t)node*64 + jt*16 + mrow] = f2h_bits(fmaxf(o, 0.f));
                    }
                }
            }else{
                float s3 = 0.f;
                #pragma unroll
                for(int jt = 0; jt < 4; ++jt){
                    float o = (acc[jt][v] - mu) * rstd * gv[jt] + bv[jt];
                    s3 += fmaxf(o, 0.f) * wo[jt];
                }
                #pragma unroll
                for(int off = 1; off <= 8; off <<= 1)
                    s3 += __shfl_xor(s3, off);
                if(mrow == 0 && node < Nk)
                    out[(size_t)b*Nk + node] = s3 + bo;
            }
        }
    }
}

// ---------------------------------------------------------------------------
extern "C" void kernel_launch(void* const* d_in, const int* in_sizes, int n_in,
                              void* d_out, int out_size, void* d_ws, size_t ws_size,
                              hipStream_t stream){
    const float* ctl        = (const float*)d_in[0];
    const float* dt         = (const float*)d_in[1];
    const float* drug_fp    = (const float*)d_in[2];
    const float* edge_w     = (const float*)d_in[3];
    const int*   cell_idx   = (const int*)  d_in[4];
    const int*   edge_index = (const int*)  d_in[5];
    const float* W_se       = (const float*)d_in[6];
    const float* b_se       = (const float*)d_in[7];
    const float* cell_emb   = (const float*)d_in[8];
    const float* W_f1       = (const float*)d_in[9];
    const float* b_f1       = (const float*)d_in[10];
    const float* W_f2       = (const float*)d_in[11];
    const float* b_f2       = (const float*)d_in[12];
    const float* Wself      = (const float*)d_in[13];
    const float* Wrel       = (const float*)d_in[14];
    const float* ln_g       = (const float*)d_in[15];
    const float* ln_b       = (const float*)d_in[16];
    const float* W_out      = (const float*)d_in[17];
    const float* b_out      = (const float*)d_in[18];
    float* out = (float*)d_out;

    char* p = (char*)d_ws;
    auto alloc = [&](size_t bytes)->char*{
        char* r = p; p += (bytes + 255) & ~(size_t)255; return r;
    };
    int*   deg    = (int*)  alloc((size_t)Rk*Nk*4);
    int*   cursor = (int*)  alloc((size_t)Rk*Nk*4);
    int*   offs   = (int*)  alloc((size_t)Rk*(Nk+1)*4);
    int2*  epack  = (int2*) alloc((size_t)Rk*Ek*8);
    float* hid    = (float*)alloc((size_t)Bk*64*4);
    float* g1p    = (float*)alloc((size_t)Bk*64*4);
    float* beta   = (float*)alloc((size_t)Bk*64*4);
    u16*   xh     = (u16*)  alloc((size_t)Bk*Nk*64*2);
    u16*   aggh   = (u16*)  alloc((size_t)3*Bk*Nk*64*2);
    u16*   wt     = (u16*)  alloc((size_t)Lk*16384*2);

    // weight prep + deg zeroing (65536 threads covers wt AND deg)
    k_wprep<<<(Lk*4*2*4*64*8 + 255)/256, 256, 0, stream>>>(Wself, Wrel, wt, deg);

    // fused prep pipeline
    k_count_film1<<<CNTB + Bk*64, 256, 0, stream>>>(edge_index, deg, drug_fp, W_f1, b_f1, hid);
    k_scan_film2<<<3 + Bk, 1024, 0, stream>>>(deg, offs, cursor, hid, W_f2, b_f2, g1p, beta);
    k_fill_init<<<CNTB + INITB, 256, 0, stream>>>(edge_index, edge_w, cursor, epack,
                                                  ctl, dt, cell_idx, W_se, b_se, cell_emb,
                                                  g1p, beta, xh);

    // layers
    const int ntile = (Nk + 127)/128;          // 79
    for(int l = 0; l < Lk; ++l){
        k_agg<<<4*7500, 256, 0, stream>>>(xh, offs, epack, aggh);
        k_proj_mfma<<<ntile*8, 256, 0, stream>>>(
            xh, aggh, wt, ln_g, ln_b, l,
            (l == Lk-1) ? 1 : 0, W_out, b_out, out);
    }
}